// Round 5
// baseline (446.597 us; speedup 1.0000x reference)
//
#include <hip/hip_runtime.h>
#include <hip/hip_bf16.h>

#define NB 256          // edge-pass blocks
#define MAXBKT 512      // supports n <= 131072

typedef __attribute__((ext_vector_type(8))) unsigned short ushort8;

__device__ __forceinline__ unsigned short f2bf(float f) {
    unsigned u = __float_as_uint(f);
    unsigned r = (u + 0x7FFF + ((u >> 16) & 1)) >> 16;   // RNE
    return (unsigned short)r;
}

// ---- pass 0: per-(srcbkt, block) histogram of src>>8 ----
__global__ __launch_bounds__(256) void k_hist_src(const int* __restrict__ row, int E, int e2,
                                                  int per, int* __restrict__ cnt, int nbkt) {
    __shared__ int h[MAXBKT];
    int t = threadIdx.x;
    for (int i = t; i < nbkt; i += 256) h[i] = 0;
    __syncthreads();
    int s = blockIdx.x * per, e = min(s + per, e2);
    for (int i = s + t; i < e; i += 256) {
        int src = (i < E) ? row[i] : i - E;
        atomicAdd(&h[src >> 8], 1);
    }
    __syncthreads();
    for (int i = t; i < nbkt; i += 256) cnt[i * NB + blockIdx.x] = h[i];
}

// ---- hierarchical exclusive scan ----
#define SCAN_T 256
#define SCAN_E 1024

__global__ void k_scan_a(const int* __restrict__ cnt, int n,
                         int* __restrict__ outp, int* __restrict__ bsum) {
    __shared__ int s[SCAN_T];
    int t = threadIdx.x, b = blockIdx.x;
    int base = b * SCAN_E + t * 4;
    int c0 = (base + 0 < n) ? cnt[base + 0] : 0;
    int c1 = (base + 1 < n) ? cnt[base + 1] : 0;
    int c2 = (base + 2 < n) ? cnt[base + 2] : 0;
    int c3 = (base + 3 < n) ? cnt[base + 3] : 0;
    int tsum = c0 + c1 + c2 + c3;
    s[t] = tsum; __syncthreads();
    for (int off = 1; off < SCAN_T; off <<= 1) {
        int v = (t >= off) ? s[t - off] : 0;
        __syncthreads();
        s[t] += v;
        __syncthreads();
    }
    int excl = s[t] - tsum;
    if (base + 0 < n) outp[base + 0] = excl;
    if (base + 1 < n) outp[base + 1] = excl + c0;
    if (base + 2 < n) outp[base + 2] = excl + c0 + c1;
    if (base + 3 < n) outp[base + 3] = excl + c0 + c1 + c2;
    if (t == 0) bsum[b] = s[SCAN_T - 1];
}

__global__ void k_scan_b(int* __restrict__ bsum, int nb) {
    __shared__ int s[128];
    int t = threadIdx.x;
    int v = (t < nb) ? bsum[t] : 0;
    s[t] = v; __syncthreads();
    for (int off = 1; off < 128; off <<= 1) {
        int u = (t >= off) ? s[t - off] : 0;
        __syncthreads();
        s[t] += u;
        __syncthreads();
    }
    if (t < nb) bsum[t] = s[t] - v;   // exclusive
}

__global__ void k_scan_c(int* __restrict__ outp, const int* __restrict__ bsum,
                         int n, int total) {
    int i = blockIdx.x * blockDim.x + threadIdx.x;
    if (i < n) outp[i] += bsum[i / SCAN_E];
    if (i == 0) outp[n] = total;
}

// ---- pass 1: scatter full records coarse-sorted by src>>8 ----
__global__ __launch_bounds__(256) void k_scatter_src(const int* __restrict__ row,
                                                     const int* __restrict__ col,
                                                     const float* __restrict__ ew,
                                                     int E, int e2, int per,
                                                     const int* __restrict__ S2,
                                                     uint4* __restrict__ recs, int nbkt) {
    __shared__ int cur[MAXBKT];
    int t = threadIdx.x;
    for (int i = t; i < nbkt; i += 256) cur[i] = S2[i * NB + blockIdx.x];
    __syncthreads();
    int s = blockIdx.x * per, e = min(s + per, e2);
    for (int i = s + t; i < e; i += 256) {
        int src, dst; float w;
        if (i < E) { src = row[i]; dst = col[i]; w = ew[i]; }
        else       { src = dst = i - E; w = 1.0f; }
        int slot = atomicAdd(&cur[src >> 8], 1);
        recs[slot] = make_uint4((unsigned)src, (unsigned)dst, __float_as_uint(w), 0u);
    }
}

// ---- pass 2: per-(dstbkt, block) histogram over src-sorted records ----
__global__ __launch_bounds__(256) void k_hist_dst(const uint4* __restrict__ recs, int e2,
                                                  int per, int* __restrict__ cnt, int nbkt) {
    __shared__ int h[MAXBKT];
    int t = threadIdx.x;
    for (int i = t; i < nbkt; i += 256) h[i] = 0;
    __syncthreads();
    int s = blockIdx.x * per, e = min(s + per, e2);
    for (int i = s + t; i < e; i += 256) atomicAdd(&h[recs[i].y >> 8], 1);
    __syncthreads();
    for (int i = t; i < nbkt; i += 256) cnt[i * NB + blockIdx.x] = h[i];
}

// ---- pass 3: scatter to dst-bucket-major slots (preserves coarse src order) ----
__global__ __launch_bounds__(256) void k_scatter1(const uint4* __restrict__ recs,
                                                  int e2, int per,
                                                  const int* __restrict__ S,
                                                  uint2* __restrict__ csrR, int nbkt) {
    __shared__ int cur[MAXBKT];
    int t = threadIdx.x;
    for (int i = t; i < nbkt; i += 256) cur[i] = S[i * NB + blockIdx.x];
    __syncthreads();
    int s = blockIdx.x * per, e = min(s + per, e2);
    for (int i = s + t; i < e; i += 256) {
        uint4 r = recs[i];
        int slot = atomicAdd(&cur[r.y >> 8], 1);
        csrR[slot] = make_uint2((r.x << 8) | (r.y & 255u), r.z);
    }
}

// ---- pass 4: per-bucket regroup by dst; emits dinv, rowptr, final CSR ----
__global__ __launch_bounds__(256) void k_build(const uint2* __restrict__ csrR,
                                               const int* __restrict__ S,
                                               int n, int e2,
                                               float2* __restrict__ csrF,
                                               float* __restrict__ dinv,
                                               int* __restrict__ rowptr, int nbkt) {
    __shared__ int   cnt[256];
    __shared__ float wsm[256];
    __shared__ int   off[256];
    __shared__ float dvs[256];
    __shared__ int   curs[256];
    int b = blockIdx.x, t = threadIdx.x;
    cnt[t] = 0; wsm[t] = 0.f;
    __syncthreads();
    int base = S[b * NB], end = S[(b + 1) * NB];   // S[nbkt*NB] == e2
    for (int i = base + t; i < end; i += 256) {
        uint2 r = csrR[i];
        int d = r.x & 255;
        atomicAdd(&cnt[d], 1);
        atomicAdd(&wsm[d], __uint_as_float(r.y));
    }
    __syncthreads();
    int   myc = cnt[t];
    float w   = wsm[t];
    float dv  = (w > 0.f) ? rsqrtf(w) : 0.f;
    dvs[t] = dv;
    off[t] = myc;
    __syncthreads();
    for (int o = 1; o < 256; o <<= 1) {
        int v = (t >= o) ? off[t - o] : 0;
        __syncthreads();
        off[t] += v;
        __syncthreads();
    }
    int excl = off[t] - myc;
    int node = b * 256 + t;
    if (node < n) { dinv[node] = dv; rowptr[node] = base + excl; }
    if (b == nbkt - 1 && t == 0) rowptr[n] = e2;
    curs[t] = excl;
    __syncthreads();
    for (int i = base + t; i < end; i += 256) {
        uint2 r = csrR[i];
        int d = r.x & 255;
        int src = (int)(r.x >> 8);
        int p = base + atomicAdd(&curs[d], 1);
        csrF[p] = make_float2(__int_as_float(src), __uint_as_float(r.y) * dvs[d]);
    }
}

// ---- GEMM (fp32 or bf16 input) -> bf16 out, row-scaled: O[r] = bf16((H@W)[r]*dinv[r]) ----
template<typename T>
__global__ __launch_bounds__(256) void k_gemm(const T* __restrict__ H,
                                              const float* __restrict__ W,
                                              const float* __restrict__ dinv,
                                              unsigned short* __restrict__ O, int n) {
    __shared__ float Hs[64][33];
    __shared__ float Ws[32][132];
    int t = threadIdx.x;
    int tx = t & 15, ty = t >> 4;
    int rowBase = blockIdx.x * 64;
    float acc[4][8] = {};
    for (int kk = 0; kk < 128; kk += 32) {
        if constexpr (sizeof(T) == 4) {
#pragma unroll
            for (int i = 0; i < 2; ++i) {
                int f4 = t + i * 256;
                int r = f4 >> 3, c = (f4 & 7) * 4;
                int gr = rowBase + r;
                float4 v = make_float4(0.f, 0.f, 0.f, 0.f);
                if (gr < n) v = *(const float4*)&H[(size_t)gr * 128 + kk + c];
                Hs[r][c + 0] = v.x; Hs[r][c + 1] = v.y;
                Hs[r][c + 2] = v.z; Hs[r][c + 3] = v.w;
            }
        } else {
            int r = t >> 2, c = (t & 3) * 8;
            int gr = rowBase + r;
            ushort8 v = {};
            if (gr < n) v = *(const ushort8*)&H[(size_t)gr * 128 + kk + c];
#pragma unroll
            for (int j = 0; j < 8; ++j)
                Hs[r][c + j] = __uint_as_float((unsigned)v[j] << 16);
        }
#pragma unroll
        for (int i = 0; i < 4; ++i) {
            int f4 = t + i * 256;
            int kr = f4 >> 5, c = (f4 & 31) * 4;
            float4 v = *(const float4*)&W[(kk + kr) * 128 + c];
            *(float4*)&Ws[kr][c] = v;
        }
        __syncthreads();
#pragma unroll
        for (int k = 0; k < 32; ++k) {
            float4 w0 = *(const float4*)&Ws[k][tx * 8];
            float4 w1 = *(const float4*)&Ws[k][tx * 8 + 4];
#pragma unroll
            for (int i = 0; i < 4; ++i) {
                float h = Hs[ty * 4 + i][k];
                acc[i][0] += h * w0.x; acc[i][1] += h * w0.y;
                acc[i][2] += h * w0.z; acc[i][3] += h * w0.w;
                acc[i][4] += h * w1.x; acc[i][5] += h * w1.y;
                acc[i][6] += h * w1.z; acc[i][7] += h * w1.w;
            }
        }
        __syncthreads();
    }
#pragma unroll
    for (int i = 0; i < 4; ++i) {
        int gr = rowBase + ty * 4 + i;
        if (gr < n) {
            float sc = dinv[gr];
            ushort8 o;
#pragma unroll
            for (int j = 0; j < 8; ++j) o[j] = f2bf(acc[i][j] * sc);
            *(ushort8*)&O[(size_t)gr * 128 + tx * 8] = o;
        }
    }
}

// ------- aggregation: 16 lanes/node, 4 nodes/wave, fp32 accum, bf16 out -------
template<bool RELU>
__global__ __launch_bounds__(256) void k_agg(const uint4* __restrict__ Hw,
                                             const int* __restrict__ rowptr,
                                             const float2* __restrict__ csr,
                                             const float* __restrict__ bias,
                                             unsigned short* __restrict__ out, int n) {
    int wv = threadIdx.x >> 6, lane = threadIdx.x & 63;
    int g = lane >> 4, sl = lane & 15;
    int node = blockIdx.x * 16 + wv * 4 + g;
    bool act = node < n;
    int s = 0, e = 0;
    if (act) { s = rowptr[node]; e = rowptr[node + 1]; }
    float a0 = 0.f, a1 = 0.f, a2 = 0.f, a3 = 0.f, a4 = 0.f, a5 = 0.f, a6 = 0.f, a7 = 0.f;

#define FMA8(V, W8) do {                                              \
    float _w = (W8);                                                  \
    a0 += __uint_as_float((V).x << 16) * _w;                          \
    a1 += __uint_as_float((V).x & 0xFFFF0000u) * _w;                  \
    a2 += __uint_as_float((V).y << 16) * _w;                          \
    a3 += __uint_as_float((V).y & 0xFFFF0000u) * _w;                  \
    a4 += __uint_as_float((V).z << 16) * _w;                          \
    a5 += __uint_as_float((V).z & 0xFFFF0000u) * _w;                  \
    a6 += __uint_as_float((V).w << 16) * _w;                          \
    a7 += __uint_as_float((V).w & 0xFFFF0000u) * _w;                  \
} while (0)

    int i = s;
    for (; i + 4 <= e; i += 4) {
        float2 p0 = csr[i + 0], p1 = csr[i + 1], p2 = csr[i + 2], p3 = csr[i + 3];
        uint4 v0 = Hw[(size_t)__float_as_int(p0.x) * 16 + sl];
        uint4 v1 = Hw[(size_t)__float_as_int(p1.x) * 16 + sl];
        uint4 v2 = Hw[(size_t)__float_as_int(p2.x) * 16 + sl];
        uint4 v3 = Hw[(size_t)__float_as_int(p3.x) * 16 + sl];
        FMA8(v0, p0.y); FMA8(v1, p1.y); FMA8(v2, p2.y); FMA8(v3, p3.y);
    }
    for (; i < e; ++i) {
        float2 p = csr[i];
        uint4 v = Hw[(size_t)__float_as_int(p.x) * 16 + sl];
        FMA8(v, p.y);
    }
#undef FMA8

    if (act) {
        const float4* b4 = (const float4*)&bias[sl * 8];
        float4 b0 = b4[0], b1 = b4[1];
        a0 += b0.x; a1 += b0.y; a2 += b0.z; a3 += b0.w;
        a4 += b1.x; a5 += b1.y; a6 += b1.z; a7 += b1.w;
        if (RELU) {
            a0 = fmaxf(a0, 0.f); a1 = fmaxf(a1, 0.f); a2 = fmaxf(a2, 0.f); a3 = fmaxf(a3, 0.f);
            a4 = fmaxf(a4, 0.f); a5 = fmaxf(a5, 0.f); a6 = fmaxf(a6, 0.f); a7 = fmaxf(a7, 0.f);
        }
        ushort8 o;
        o[0] = f2bf(a0); o[1] = f2bf(a1); o[2] = f2bf(a2); o[3] = f2bf(a3);
        o[4] = f2bf(a4); o[5] = f2bf(a5); o[6] = f2bf(a6); o[7] = f2bf(a7);
        *(ushort8*)&out[(size_t)node * 128 + sl * 8] = o;
    }
}

// ---------------- fused mean-pool + final linear (bf16 input) ----------------
__device__ __forceinline__ int lower_bound_i(const int* a, int n, int key) {
    int lo = 0, hi = n;
    while (lo < hi) { int mid = (lo + hi) >> 1; if (a[mid] < key) lo = mid + 1; else hi = mid; }
    return lo;
}

__global__ void k_pool(const unsigned* __restrict__ H, const int* __restrict__ batch,
                       const float* __restrict__ Wlin, const float* __restrict__ blin,
                       float* __restrict__ out, int n) {
    int g = blockIdx.x;
    int start = lower_bound_i(batch, n, g);
    int end   = lower_bound_i(batch, n, g + 1);
    int t = threadIdx.x;
    int wid = t >> 6, lane = t & 63;
    float ax = 0.f, ay = 0.f;
    for (int i = start + wid; i < end; i += 4) {
        unsigned u = H[(size_t)i * 64 + lane];
        ax += __uint_as_float(u << 16);
        ay += __uint_as_float(u & 0xFFFF0000u);
    }
    __shared__ float ws[4][128];
    __shared__ float hg[128];
    ws[wid][lane * 2] = ax; ws[wid][lane * 2 + 1] = ay;
    __syncthreads();
    int cnt = end - start;
    float inv = 1.0f / fmaxf((float)cnt, 1.0f);
    if (t < 128) hg[t] = (ws[0][t] + ws[1][t] + ws[2][t] + ws[3][t]) * inv;
    __syncthreads();
    if (t < 16) {
        float s = blin[t];
        for (int ch = 0; ch < 128; ++ch) s += hg[ch] * Wlin[ch * 16 + t];
        out[g * 16 + t] = s;
    }
}

// ---------------- host ----------------
extern "C" void kernel_launch(void* const* d_in, const int* in_sizes, int n_in,
                              void* d_out, int out_size, void* d_ws, size_t ws_size,
                              hipStream_t stream) {
    const float* x    = (const float*)d_in[0];
    const int*   ei   = (const int*)d_in[1];
    const float* ew   = (const float*)d_in[2];
    const int*   batch= (const int*)d_in[3];
    const float* W1   = (const float*)d_in[4];
    const float* b1   = (const float*)d_in[5];
    const float* W2   = (const float*)d_in[6];
    const float* b2   = (const float*)d_in[7];
    const float* W3   = (const float*)d_in[8];
    const float* b3   = (const float*)d_in[9];
    const float* Wlin = (const float*)d_in[10];
    const float* blin = (const float*)d_in[11];
    float* out = (float*)d_out;

    int n  = in_sizes[0] / 128;
    int E  = in_sizes[2];
    int e2 = E + n;
    int G  = out_size / 16;
    const int* row = ei;
    const int* col = ei + E;

    int nbkt = (n + 255) >> 8;          // 256 nodes per bucket
    int M    = nbkt * NB;

    char* ws = (char*)d_ws;
    size_t off = 0;
    auto alloc = [&](size_t bytes) -> void* {
        void* p = ws + off;
        off = (off + bytes + 255) & ~255UL;
        return p;
    };
    // regionA: {recs (e2*16B) @0, csrR (e2*8B) after} during pre; bf16 h (n*256B) later
    size_t recsBytes = ((size_t)e2 * 16 + 255) & ~255UL;
    size_t preBytes  = recsBytes + (size_t)e2 * 8;
    size_t hBytes    = (size_t)n * 128 * 2;
    void* regionA = alloc(preBytes > hBytes ? preBytes : hBytes);
    uint4*  recs  = (uint4*)regionA;
    uint2*  csrR  = (uint2*)((char*)regionA + recsBytes);
    unsigned short* bufH = (unsigned short*)regionA;        // aliases recs/csrR after k_build
    unsigned short* bufHw = (unsigned short*)alloc((size_t)n * 128 * 2);
    float2* csrF  = (float2*)alloc((size_t)e2 * 8);
    int*    cntA  = (int*)  alloc((size_t)M * 4);
    int*    S     = (int*)  alloc((size_t)(M + 1) * 4);
    int*    cntB  = (int*)  alloc((size_t)M * 4);
    int*    S2    = (int*)  alloc((size_t)(M + 1) * 4);
    int*    bsum  = (int*)  alloc(4096);
    float*  dinv  = (float*)alloc((size_t)n * 4);
    int*    rowptr= (int*)  alloc((size_t)(n + 1) * 4);
    (void)ws_size;

    int per = (e2 + NB - 1) / NB;
    int nbScan = (M + SCAN_E - 1) / SCAN_E;

    // src coarse sort
    k_hist_src<<<NB, 256, 0, stream>>>(row, E, e2, per, cntB, nbkt);
    k_scan_a<<<nbScan, SCAN_T, 0, stream>>>(cntB, M, S2, bsum);
    k_scan_b<<<1, 128, 0, stream>>>(bsum, nbScan);
    k_scan_c<<<(M + 255) / 256, 256, 0, stream>>>(S2, bsum, M, e2);
    k_scatter_src<<<NB, 256, 0, stream>>>(row, col, ew, E, e2, per, S2, recs, nbkt);

    // dst sort (stable w.r.t. src coarse order)
    k_hist_dst<<<NB, 256, 0, stream>>>(recs, e2, per, cntA, nbkt);
    k_scan_a<<<nbScan, SCAN_T, 0, stream>>>(cntA, M, S, bsum);
    k_scan_b<<<1, 128, 0, stream>>>(bsum, nbScan);
    k_scan_c<<<(M + 255) / 256, 256, 0, stream>>>(S, bsum, M, e2);
    k_scatter1<<<NB, 256, 0, stream>>>(recs, e2, per, S, csrR, nbkt);
    k_build<<<nbkt, 256, 0, stream>>>(csrR, S, n, e2, csrF, dinv, rowptr, nbkt);

    int gb = (n + 63) / 64;
    int ab = (n + 15) / 16;
    k_gemm<float><<<gb, 256, 0, stream>>>(x, W1, dinv, bufHw, n);
    k_agg<true><<<ab, 256, 0, stream>>>((const uint4*)bufHw, rowptr, csrF, b1, bufH, n);
    k_gemm<unsigned short><<<gb, 256, 0, stream>>>(bufH, W2, dinv, bufHw, n);
    k_agg<true><<<ab, 256, 0, stream>>>((const uint4*)bufHw, rowptr, csrF, b2, bufH, n);
    k_gemm<unsigned short><<<gb, 256, 0, stream>>>(bufH, W3, dinv, bufHw, n);
    k_agg<false><<<ab, 256, 0, stream>>>((const uint4*)bufHw, rowptr, csrF, b3, bufH, n);
    k_pool<<<G, 256, 0, stream>>>((const unsigned*)bufH, batch, Wlin, blin, out, n);
}

// Round 6
// 411.609 us; speedup vs baseline: 1.0850x; 1.0850x over previous
//
#include <hip/hip_runtime.h>
#include <hip/hip_bf16.h>

#define NB 256          // edge-pass blocks
#define MAXBKT 512      // supports n <= 131072

typedef __attribute__((ext_vector_type(8))) unsigned short ushort8;
typedef __attribute__((ext_vector_type(8))) short bf16x8;
typedef __attribute__((ext_vector_type(4))) float f32x4;

__device__ __forceinline__ unsigned short f2bf(float f) {
    unsigned u = __float_as_uint(f);
    unsigned r = (u + 0x7FFF + ((u >> 16) & 1)) >> 16;   // RNE
    return (unsigned short)r;
}

// ---- pass 0: per-(srcbkt, block) histogram of src>>8 ----
__global__ __launch_bounds__(256) void k_hist_src(const int* __restrict__ row, int E, int e2,
                                                  int per, int* __restrict__ cnt, int nbkt) {
    __shared__ int h[MAXBKT];
    int t = threadIdx.x;
    for (int i = t; i < nbkt; i += 256) h[i] = 0;
    __syncthreads();
    int s = blockIdx.x * per, e = min(s + per, e2);
    for (int i = s + t; i < e; i += 256) {
        int src = (i < E) ? row[i] : i - E;
        atomicAdd(&h[src >> 8], 1);
    }
    __syncthreads();
    for (int i = t; i < nbkt; i += 256) cnt[i * NB + blockIdx.x] = h[i];
}

// ---- hierarchical exclusive scan ----
#define SCAN_T 256
#define SCAN_E 1024

__global__ void k_scan_a(const int* __restrict__ cnt, int n,
                         int* __restrict__ outp, int* __restrict__ bsum) {
    __shared__ int s[SCAN_T];
    int t = threadIdx.x, b = blockIdx.x;
    int base = b * SCAN_E + t * 4;
    int c0 = (base + 0 < n) ? cnt[base + 0] : 0;
    int c1 = (base + 1 < n) ? cnt[base + 1] : 0;
    int c2 = (base + 2 < n) ? cnt[base + 2] : 0;
    int c3 = (base + 3 < n) ? cnt[base + 3] : 0;
    int tsum = c0 + c1 + c2 + c3;
    s[t] = tsum; __syncthreads();
    for (int off = 1; off < SCAN_T; off <<= 1) {
        int v = (t >= off) ? s[t - off] : 0;
        __syncthreads();
        s[t] += v;
        __syncthreads();
    }
    int excl = s[t] - tsum;
    if (base + 0 < n) outp[base + 0] = excl;
    if (base + 1 < n) outp[base + 1] = excl + c0;
    if (base + 2 < n) outp[base + 2] = excl + c0 + c1;
    if (base + 3 < n) outp[base + 3] = excl + c0 + c1 + c2;
    if (t == 0) bsum[b] = s[SCAN_T - 1];
}

__global__ void k_scan_b(int* __restrict__ bsum, int nb) {
    __shared__ int s[128];
    int t = threadIdx.x;
    int v = (t < nb) ? bsum[t] : 0;
    s[t] = v; __syncthreads();
    for (int off = 1; off < 128; off <<= 1) {
        int u = (t >= off) ? s[t - off] : 0;
        __syncthreads();
        s[t] += u;
        __syncthreads();
    }
    if (t < nb) bsum[t] = s[t] - v;   // exclusive
}

__global__ void k_scan_c(int* __restrict__ outp, const int* __restrict__ bsum,
                         int n, int total) {
    int i = blockIdx.x * blockDim.x + threadIdx.x;
    if (i < n) outp[i] += bsum[i / SCAN_E];
    if (i == 0) outp[n] = total;
}

// ---- pass 1: scatter full records coarse-sorted by src>>8 ----
__global__ __launch_bounds__(256) void k_scatter_src(const int* __restrict__ row,
                                                     const int* __restrict__ col,
                                                     const float* __restrict__ ew,
                                                     int E, int e2, int per,
                                                     const int* __restrict__ S2,
                                                     uint4* __restrict__ recs, int nbkt) {
    __shared__ int cur[MAXBKT];
    int t = threadIdx.x;
    for (int i = t; i < nbkt; i += 256) cur[i] = S2[i * NB + blockIdx.x];
    __syncthreads();
    int s = blockIdx.x * per, e = min(s + per, e2);
    for (int i = s + t; i < e; i += 256) {
        int src, dst; float w;
        if (i < E) { src = row[i]; dst = col[i]; w = ew[i]; }
        else       { src = dst = i - E; w = 1.0f; }
        int slot = atomicAdd(&cur[src >> 8], 1);
        recs[slot] = make_uint4((unsigned)src, (unsigned)dst, __float_as_uint(w), 0u);
    }
}

// ---- pass 2: per-(dstbkt, block) histogram over src-sorted records ----
__global__ __launch_bounds__(256) void k_hist_dst(const uint4* __restrict__ recs, int e2,
                                                  int per, int* __restrict__ cnt, int nbkt) {
    __shared__ int h[MAXBKT];
    int t = threadIdx.x;
    for (int i = t; i < nbkt; i += 256) h[i] = 0;
    __syncthreads();
    int s = blockIdx.x * per, e = min(s + per, e2);
    for (int i = s + t; i < e; i += 256) atomicAdd(&h[recs[i].y >> 8], 1);
    __syncthreads();
    for (int i = t; i < nbkt; i += 256) cnt[i * NB + blockIdx.x] = h[i];
}

// ---- pass 3: scatter to dst-bucket-major slots (preserves coarse src order) ----
__global__ __launch_bounds__(256) void k_scatter1(const uint4* __restrict__ recs,
                                                  int e2, int per,
                                                  const int* __restrict__ S,
                                                  uint2* __restrict__ csrR, int nbkt) {
    __shared__ int cur[MAXBKT];
    int t = threadIdx.x;
    for (int i = t; i < nbkt; i += 256) cur[i] = S[i * NB + blockIdx.x];
    __syncthreads();
    int s = blockIdx.x * per, e = min(s + per, e2);
    for (int i = s + t; i < e; i += 256) {
        uint4 r = recs[i];
        int slot = atomicAdd(&cur[r.y >> 8], 1);
        csrR[slot] = make_uint2((r.x << 8) | (r.y & 255u), r.z);
    }
}

// ---- pass 4: per-bucket regroup by dst; emits dinv, rowptr, final CSR ----
__global__ __launch_bounds__(256) void k_build(const uint2* __restrict__ csrR,
                                               const int* __restrict__ S,
                                               int n, int e2,
                                               float2* __restrict__ csrF,
                                               float* __restrict__ dinv,
                                               int* __restrict__ rowptr, int nbkt) {
    __shared__ int   cnt[256];
    __shared__ float wsm[256];
    __shared__ int   off[256];
    __shared__ float dvs[256];
    __shared__ int   curs[256];
    int b = blockIdx.x, t = threadIdx.x;
    cnt[t] = 0; wsm[t] = 0.f;
    __syncthreads();
    int base = S[b * NB], end = S[(b + 1) * NB];   // S[nbkt*NB] == e2
    for (int i = base + t; i < end; i += 256) {
        uint2 r = csrR[i];
        int d = r.x & 255;
        atomicAdd(&cnt[d], 1);
        atomicAdd(&wsm[d], __uint_as_float(r.y));
    }
    __syncthreads();
    int   myc = cnt[t];
    float w   = wsm[t];
    float dv  = (w > 0.f) ? rsqrtf(w) : 0.f;
    dvs[t] = dv;
    off[t] = myc;
    __syncthreads();
    for (int o = 1; o < 256; o <<= 1) {
        int v = (t >= o) ? off[t - o] : 0;
        __syncthreads();
        off[t] += v;
        __syncthreads();
    }
    int excl = off[t] - myc;
    int node = b * 256 + t;
    if (node < n) { dinv[node] = dv; rowptr[node] = base + excl; }
    if (b == nbkt - 1 && t == 0) rowptr[n] = e2;
    curs[t] = excl;
    __syncthreads();
    for (int i = base + t; i < end; i += 256) {
        uint2 r = csrR[i];
        int d = r.x & 255;
        int src = (int)(r.x >> 8);
        int p = base + atomicAdd(&curs[d], 1);
        csrF[p] = make_float2(__int_as_float(src), __uint_as_float(r.y) * dvs[d]);
    }
}

// ---- weight transpose+convert: WT[n][k] = bf16(W[k][n]), 128x128 ----
__global__ __launch_bounds__(256) void k_wt(const float* __restrict__ W,
                                            unsigned short* __restrict__ WT) {
    int idx = blockIdx.x * 256 + threadIdx.x;      // 16384 total
    int nn = idx >> 7, k = idx & 127;
    WT[nn * 128 + k] = f2bf(W[k * 128 + nn]);      // write coalesced
}

// ---- MFMA GEMM: O[r] = bf16((H@W)[r] * dinv[r]); H fp32 or bf16; WT = W^T bf16 ----
// block = 4 waves, each wave: 16 rows x 128 cols, K=128 via 4x mfma 16x16x32 per col-tile.
// No LDS, no barriers: A frags = 16B/lane streaming loads, B frags = L1-hot WT loads.
template<typename T>
__global__ __launch_bounds__(256) void k_gemm_mfma(const T* __restrict__ H,
                                                   const unsigned short* __restrict__ WT,
                                                   const float* __restrict__ dinv,
                                                   unsigned short* __restrict__ O, int n) {
    int wv = threadIdx.x >> 6, lane = threadIdx.x & 63;
    int rowBase = blockIdx.x * 64 + wv * 16;
    int lr = lane & 15;            // A row / B col / D col within tile
    int lk = (lane >> 4) * 8;      // k offset within 32-chunk

    int arow = min(rowBase + lr, n - 1);
    bf16x8 a[4];
#pragma unroll
    for (int kk = 0; kk < 4; ++kk) {
        if constexpr (sizeof(T) == 4) {
            const float4* p = (const float4*)&H[(size_t)arow * 128 + kk * 32 + lk];
            float4 h0 = p[0], h1 = p[1];
            bf16x8 av;
            av[0] = (short)f2bf(h0.x); av[1] = (short)f2bf(h0.y);
            av[2] = (short)f2bf(h0.z); av[3] = (short)f2bf(h0.w);
            av[4] = (short)f2bf(h1.x); av[5] = (short)f2bf(h1.y);
            av[6] = (short)f2bf(h1.z); av[7] = (short)f2bf(h1.w);
            a[kk] = av;
        } else {
            a[kk] = *(const bf16x8*)&H[(size_t)arow * 128 + kk * 32 + lk];
        }
    }

    f32x4 acc[8] = {};
#pragma unroll
    for (int c = 0; c < 8; ++c) {
#pragma unroll
        for (int kk = 0; kk < 4; ++kk) {
            bf16x8 b = *(const bf16x8*)&WT[(size_t)(c * 16 + lr) * 128 + kk * 32 + lk];
            acc[c] = __builtin_amdgcn_mfma_f32_16x16x32_bf16(a[kk], b, acc[c], 0, 0, 0);
        }
    }

    // D mapping (HW-verified): col = lane&15 (channel within tile), row = (lane>>4)*4+r (node)
#pragma unroll
    for (int r = 0; r < 4; ++r) {
        int node = rowBase + (lane >> 4) * 4 + r;
        if (node < n) {
            float sc = dinv[node];
#pragma unroll
            for (int c = 0; c < 8; ++c)
                O[(size_t)node * 128 + c * 16 + lr] = f2bf(acc[c][r] * sc);
        }
    }
}

// ------- aggregation: 16 lanes/node, 4 nodes/wave, fp32 accum, bf16 out -------
template<bool RELU>
__global__ __launch_bounds__(256) void k_agg(const uint4* __restrict__ Hw,
                                             const int* __restrict__ rowptr,
                                             const float2* __restrict__ csr,
                                             const float* __restrict__ bias,
                                             unsigned short* __restrict__ out, int n) {
    int wv = threadIdx.x >> 6, lane = threadIdx.x & 63;
    int g = lane >> 4, sl = lane & 15;
    int node = blockIdx.x * 16 + wv * 4 + g;
    bool act = node < n;
    int s = 0, e = 0;
    if (act) { s = rowptr[node]; e = rowptr[node + 1]; }
    float a0 = 0.f, a1 = 0.f, a2 = 0.f, a3 = 0.f, a4 = 0.f, a5 = 0.f, a6 = 0.f, a7 = 0.f;

#define FMA8(V, W8) do {                                              \
    float _w = (W8);                                                  \
    a0 += __uint_as_float((V).x << 16) * _w;                          \
    a1 += __uint_as_float((V).x & 0xFFFF0000u) * _w;                  \
    a2 += __uint_as_float((V).y << 16) * _w;                          \
    a3 += __uint_as_float((V).y & 0xFFFF0000u) * _w;                  \
    a4 += __uint_as_float((V).z << 16) * _w;                          \
    a5 += __uint_as_float((V).z & 0xFFFF0000u) * _w;                  \
    a6 += __uint_as_float((V).w << 16) * _w;                          \
    a7 += __uint_as_float((V).w & 0xFFFF0000u) * _w;                  \
} while (0)

    int i = s;
    for (; i + 4 <= e; i += 4) {
        float2 p0 = csr[i + 0], p1 = csr[i + 1], p2 = csr[i + 2], p3 = csr[i + 3];
        uint4 v0 = Hw[(size_t)__float_as_int(p0.x) * 16 + sl];
        uint4 v1 = Hw[(size_t)__float_as_int(p1.x) * 16 + sl];
        uint4 v2 = Hw[(size_t)__float_as_int(p2.x) * 16 + sl];
        uint4 v3 = Hw[(size_t)__float_as_int(p3.x) * 16 + sl];
        FMA8(v0, p0.y); FMA8(v1, p1.y); FMA8(v2, p2.y); FMA8(v3, p3.y);
    }
    for (; i < e; ++i) {
        float2 p = csr[i];
        uint4 v = Hw[(size_t)__float_as_int(p.x) * 16 + sl];
        FMA8(v, p.y);
    }
#undef FMA8

    if (act) {
        const float4* b4 = (const float4*)&bias[sl * 8];
        float4 b0 = b4[0], b1 = b4[1];
        a0 += b0.x; a1 += b0.y; a2 += b0.z; a3 += b0.w;
        a4 += b1.x; a5 += b1.y; a6 += b1.z; a7 += b1.w;
        if (RELU) {
            a0 = fmaxf(a0, 0.f); a1 = fmaxf(a1, 0.f); a2 = fmaxf(a2, 0.f); a3 = fmaxf(a3, 0.f);
            a4 = fmaxf(a4, 0.f); a5 = fmaxf(a5, 0.f); a6 = fmaxf(a6, 0.f); a7 = fmaxf(a7, 0.f);
        }
        ushort8 o;
        o[0] = f2bf(a0); o[1] = f2bf(a1); o[2] = f2bf(a2); o[3] = f2bf(a3);
        o[4] = f2bf(a4); o[5] = f2bf(a5); o[6] = f2bf(a6); o[7] = f2bf(a7);
        *(ushort8*)&out[(size_t)node * 128 + sl * 8] = o;
    }
}

// ---------------- fused mean-pool + final linear (bf16 input) ----------------
__device__ __forceinline__ int lower_bound_i(const int* a, int n, int key) {
    int lo = 0, hi = n;
    while (lo < hi) { int mid = (lo + hi) >> 1; if (a[mid] < key) lo = mid + 1; else hi = mid; }
    return lo;
}

__global__ void k_pool(const unsigned* __restrict__ H, const int* __restrict__ batch,
                       const float* __restrict__ Wlin, const float* __restrict__ blin,
                       float* __restrict__ out, int n) {
    int g = blockIdx.x;
    int start = lower_bound_i(batch, n, g);
    int end   = lower_bound_i(batch, n, g + 1);
    int t = threadIdx.x;
    int wid = t >> 6, lane = t & 63;
    float ax = 0.f, ay = 0.f;
    for (int i = start + wid; i < end; i += 4) {
        unsigned u = H[(size_t)i * 64 + lane];
        ax += __uint_as_float(u << 16);
        ay += __uint_as_float(u & 0xFFFF0000u);
    }
    __shared__ float ws[4][128];
    __shared__ float hg[128];
    ws[wid][lane * 2] = ax; ws[wid][lane * 2 + 1] = ay;
    __syncthreads();
    int cnt = end - start;
    float inv = 1.0f / fmaxf((float)cnt, 1.0f);
    if (t < 128) hg[t] = (ws[0][t] + ws[1][t] + ws[2][t] + ws[3][t]) * inv;
    __syncthreads();
    if (t < 16) {
        float s = blin[t];
        for (int ch = 0; ch < 128; ++ch) s += hg[ch] * Wlin[ch * 16 + t];
        out[g * 16 + t] = s;
    }
}

// ---------------- host ----------------
extern "C" void kernel_launch(void* const* d_in, const int* in_sizes, int n_in,
                              void* d_out, int out_size, void* d_ws, size_t ws_size,
                              hipStream_t stream) {
    const float* x    = (const float*)d_in[0];
    const int*   ei   = (const int*)d_in[1];
    const float* ew   = (const float*)d_in[2];
    const int*   batch= (const int*)d_in[3];
    const float* W1   = (const float*)d_in[4];
    const float* b1   = (const float*)d_in[5];
    const float* W2   = (const float*)d_in[6];
    const float* b2   = (const float*)d_in[7];
    const float* W3   = (const float*)d_in[8];
    const float* b3   = (const float*)d_in[9];
    const float* Wlin = (const float*)d_in[10];
    const float* blin = (const float*)d_in[11];
    float* out = (float*)d_out;

    int n  = in_sizes[0] / 128;
    int E  = in_sizes[2];
    int e2 = E + n;
    int G  = out_size / 16;
    const int* row = ei;
    const int* col = ei + E;

    int nbkt = (n + 255) >> 8;          // 256 nodes per bucket
    int M    = nbkt * NB;

    char* ws = (char*)d_ws;
    size_t off = 0;
    auto alloc = [&](size_t bytes) -> void* {
        void* p = ws + off;
        off = (off + bytes + 255) & ~255UL;
        return p;
    };
    // regionA: {recs (e2*16B) @0, csrR (e2*8B) after} during pre; bf16 h (n*256B) later
    size_t recsBytes = ((size_t)e2 * 16 + 255) & ~255UL;
    size_t preBytes  = recsBytes + (size_t)e2 * 8;
    size_t hBytes    = (size_t)n * 128 * 2;
    void* regionA = alloc(preBytes > hBytes ? preBytes : hBytes);
    uint4*  recs  = (uint4*)regionA;
    uint2*  csrR  = (uint2*)((char*)regionA + recsBytes);
    unsigned short* bufH = (unsigned short*)regionA;        // aliases recs/csrR after k_build
    unsigned short* bufHw = (unsigned short*)alloc((size_t)n * 128 * 2);
    float2* csrF  = (float2*)alloc((size_t)e2 * 8);
    int*    cntA  = (int*)  alloc((size_t)M * 4);
    int*    S     = (int*)  alloc((size_t)(M + 1) * 4);
    int*    cntB  = (int*)  alloc((size_t)M * 4);
    int*    S2    = (int*)  alloc((size_t)(M + 1) * 4);
    int*    bsum  = (int*)  alloc(4096);
    float*  dinv  = (float*)alloc((size_t)n * 4);
    int*    rowptr= (int*)  alloc((size_t)(n + 1) * 4);
    unsigned short* WT1 = (unsigned short*)alloc(128 * 128 * 2);
    unsigned short* WT2 = (unsigned short*)alloc(128 * 128 * 2);
    unsigned short* WT3 = (unsigned short*)alloc(128 * 128 * 2);
    (void)ws_size;

    int per = (e2 + NB - 1) / NB;
    int nbScan = (M + SCAN_E - 1) / SCAN_E;

    // weight transpose+convert (independent; cheap)
    k_wt<<<64, 256, 0, stream>>>(W1, WT1);
    k_wt<<<64, 256, 0, stream>>>(W2, WT2);
    k_wt<<<64, 256, 0, stream>>>(W3, WT3);

    // src coarse sort
    k_hist_src<<<NB, 256, 0, stream>>>(row, E, e2, per, cntB, nbkt);
    k_scan_a<<<nbScan, SCAN_T, 0, stream>>>(cntB, M, S2, bsum);
    k_scan_b<<<1, 128, 0, stream>>>(bsum, nbScan);
    k_scan_c<<<(M + 255) / 256, 256, 0, stream>>>(S2, bsum, M, e2);
    k_scatter_src<<<NB, 256, 0, stream>>>(row, col, ew, E, e2, per, S2, recs, nbkt);

    // dst sort (stable w.r.t. src coarse order)
    k_hist_dst<<<NB, 256, 0, stream>>>(recs, e2, per, cntA, nbkt);
    k_scan_a<<<nbScan, SCAN_T, 0, stream>>>(cntA, M, S, bsum);
    k_scan_b<<<1, 128, 0, stream>>>(bsum, nbScan);
    k_scan_c<<<(M + 255) / 256, 256, 0, stream>>>(S, bsum, M, e2);
    k_scatter1<<<NB, 256, 0, stream>>>(recs, e2, per, S, csrR, nbkt);
    k_build<<<nbkt, 256, 0, stream>>>(csrR, S, n, e2, csrF, dinv, rowptr, nbkt);

    int gb = (n + 63) / 64;
    int ab = (n + 15) / 16;
    k_gemm_mfma<float><<<gb, 256, 0, stream>>>(x, WT1, dinv, bufHw, n);
    k_agg<true><<<ab, 256, 0, stream>>>((const uint4*)bufHw, rowptr, csrF, b1, bufH, n);
    k_gemm_mfma<unsigned short><<<gb, 256, 0, stream>>>(bufH, WT2, dinv, bufHw, n);
    k_agg<true><<<ab, 256, 0, stream>>>((const uint4*)bufHw, rowptr, csrF, b2, bufH, n);
    k_gemm_mfma<unsigned short><<<gb, 256, 0, stream>>>(bufH, WT3, dinv, bufHw, n);
    k_agg<false><<<ab, 256, 0, stream>>>((const uint4*)bufHw, rowptr, csrF, b3, bufH, n);
    k_pool<<<G, 256, 0, stream>>>((const unsigned*)bufH, batch, Wlin, blin, out, n);
}

// Round 9
// 394.450 us; speedup vs baseline: 1.1322x; 1.0435x over previous
//
#include <hip/hip_runtime.h>
#include <hip/hip_bf16.h>

#define NB 256          // edge-pass blocks
#define MAXBKT 512      // supports n <= 131072

typedef __attribute__((ext_vector_type(8))) unsigned short ushort8;
typedef __attribute__((ext_vector_type(8))) short bf16x8;
typedef __attribute__((ext_vector_type(4))) float f32x4;

__device__ __forceinline__ unsigned short f2bf(float f) {
    unsigned u = __float_as_uint(f);
    unsigned r = (u + 0x7FFF + ((u >> 16) & 1)) >> 16;   // RNE
    return (unsigned short)r;
}

// ---- pass 1: per-(dstbkt, block) histogram of dst>>8 (zero global atomics) ----
__global__ __launch_bounds__(256) void k_hist1(const int* __restrict__ col, int E, int e2,
                                               int per, int* __restrict__ cnt, int nbkt) {
    __shared__ int h[MAXBKT];
    int t = threadIdx.x;
    for (int i = t; i < nbkt; i += 256) h[i] = 0;
    __syncthreads();
    int s = blockIdx.x * per, e = min(s + per, e2);
    for (int i = s + t; i < e; i += 256) {
        int dst = (i < E) ? col[i] : i - E;
        atomicAdd(&h[dst >> 8], 1);
    }
    __syncthreads();
    for (int i = t; i < nbkt; i += 256) cnt[i * NB + blockIdx.x] = h[i];
}

// ---- hierarchical exclusive scan ----
#define SCAN_T 256
#define SCAN_E 1024

__global__ void k_scan_a(const int* __restrict__ cnt, int n,
                         int* __restrict__ outp, int* __restrict__ bsum) {
    __shared__ int s[SCAN_T];
    int t = threadIdx.x, b = blockIdx.x;
    int base = b * SCAN_E + t * 4;
    int c0 = (base + 0 < n) ? cnt[base + 0] : 0;
    int c1 = (base + 1 < n) ? cnt[base + 1] : 0;
    int c2 = (base + 2 < n) ? cnt[base + 2] : 0;
    int c3 = (base + 3 < n) ? cnt[base + 3] : 0;
    int tsum = c0 + c1 + c2 + c3;
    s[t] = tsum; __syncthreads();
    for (int off = 1; off < SCAN_T; off <<= 1) {
        int v = (t >= off) ? s[t - off] : 0;
        __syncthreads();
        s[t] += v;
        __syncthreads();
    }
    int excl = s[t] - tsum;
    if (base + 0 < n) outp[base + 0] = excl;
    if (base + 1 < n) outp[base + 1] = excl + c0;
    if (base + 2 < n) outp[base + 2] = excl + c0 + c1;
    if (base + 3 < n) outp[base + 3] = excl + c0 + c1 + c2;
    if (t == 0) bsum[b] = s[SCAN_T - 1];
}

__global__ void k_scan_b(int* __restrict__ bsum, int nb) {
    __shared__ int s[128];
    int t = threadIdx.x;
    int v = (t < nb) ? bsum[t] : 0;
    s[t] = v; __syncthreads();
    for (int off = 1; off < 128; off <<= 1) {
        int u = (t >= off) ? s[t - off] : 0;
        __syncthreads();
        s[t] += u;
        __syncthreads();
    }
    if (t < nb) bsum[t] = s[t] - v;   // exclusive
}

__global__ void k_scan_c(int* __restrict__ outp, const int* __restrict__ bsum,
                         int n, int total) {
    int i = blockIdx.x * blockDim.x + threadIdx.x;
    if (i < n) outp[i] += bsum[i / SCAN_E];
    if (i == 0) outp[n] = total;
}

// ---- pass 3: scatter edges to exact dst-bucket-major slots (zero global atomics) ----
__global__ __launch_bounds__(256) void k_scatter1(const int* __restrict__ row,
                                                  const int* __restrict__ col,
                                                  const float* __restrict__ ew,
                                                  int E, int e2, int per,
                                                  const int* __restrict__ S,
                                                  uint2* __restrict__ csrR, int nbkt) {
    __shared__ int cur[MAXBKT];
    int t = threadIdx.x;
    for (int i = t; i < nbkt; i += 256) cur[i] = S[i * NB + blockIdx.x];
    __syncthreads();
    int s = blockIdx.x * per, e = min(s + per, e2);
    for (int i = s + t; i < e; i += 256) {
        int src, dst; float w;
        if (i < E) { src = row[i]; dst = col[i]; w = ew[i]; }
        else       { src = dst = i - E; w = 1.0f; }
        int slot = atomicAdd(&cur[dst >> 8], 1);
        csrR[slot] = make_uint2(((unsigned)src << 8) | (unsigned)(dst & 255),
                                __float_as_uint(w));
    }
}

// ---- pass 4: per-bucket regroup by dst; emits dinv, rowptr, final CSR ----
__global__ __launch_bounds__(256) void k_build(const uint2* __restrict__ csrR,
                                               const int* __restrict__ S,
                                               int n, int e2,
                                               float2* __restrict__ csrF,
                                               float* __restrict__ dinv,
                                               int* __restrict__ rowptr, int nbkt) {
    __shared__ int   cnt[256];
    __shared__ float wsm[256];
    __shared__ int   off[256];
    __shared__ float dvs[256];
    __shared__ int   curs[256];
    int b = blockIdx.x, t = threadIdx.x;
    cnt[t] = 0; wsm[t] = 0.f;
    __syncthreads();
    int base = S[b * NB], end = S[(b + 1) * NB];   // S[nbkt*NB] == e2
    for (int i = base + t; i < end; i += 256) {
        uint2 r = csrR[i];
        int d = r.x & 255;
        atomicAdd(&cnt[d], 1);
        atomicAdd(&wsm[d], __uint_as_float(r.y));
    }
    __syncthreads();
    int   myc = cnt[t];
    float w   = wsm[t];
    float dv  = (w > 0.f) ? rsqrtf(w) : 0.f;
    dvs[t] = dv;
    off[t] = myc;
    __syncthreads();
    for (int o = 1; o < 256; o <<= 1) {
        int v = (t >= o) ? off[t - o] : 0;
        __syncthreads();
        off[t] += v;
        __syncthreads();
    }
    int excl = off[t] - myc;
    int node = b * 256 + t;
    if (node < n) { dinv[node] = dv; rowptr[node] = base + excl; }
    if (b == nbkt - 1 && t == 0) rowptr[n] = e2;
    curs[t] = excl;
    __syncthreads();
    for (int i = base + t; i < end; i += 256) {
        uint2 r = csrR[i];
        int d = r.x & 255;
        int src = (int)(r.x >> 8);
        int p = base + atomicAdd(&curs[d], 1);
        csrF[p] = make_float2(__int_as_float(src), __uint_as_float(r.y) * dvs[d]);
    }
}

// ---- weight transpose+convert: WT[n][k] = bf16(W[k][n]), 128x128 ----
__global__ __launch_bounds__(256) void k_wt(const float* __restrict__ W,
                                            unsigned short* __restrict__ WT) {
    int idx = blockIdx.x * 256 + threadIdx.x;      // 16384 total
    int nn = idx >> 7, k = idx & 127;
    WT[nn * 128 + k] = f2bf(W[k * 128 + nn]);      // write coalesced
}

// ---- MFMA GEMM: O[r] = bf16((H@W)[r] * dinv[r]); H fp32 or bf16; WT = W^T bf16 ----
template<typename T>
__global__ __launch_bounds__(256) void k_gemm_mfma(const T* __restrict__ H,
                                                   const unsigned short* __restrict__ WT,
                                                   const float* __restrict__ dinv,
                                                   unsigned short* __restrict__ O, int n) {
    int wv = threadIdx.x >> 6, lane = threadIdx.x & 63;
    int rowBase = blockIdx.x * 64 + wv * 16;
    int lr = lane & 15;            // A row / B col / D col within tile
    int lk = (lane >> 4) * 8;      // k offset within 32-chunk

    int arow = min(rowBase + lr, n - 1);
    bf16x8 a[4];
#pragma unroll
    for (int kk = 0; kk < 4; ++kk) {
        if constexpr (sizeof(T) == 4) {
            const float4* p = (const float4*)&H[(size_t)arow * 128 + kk * 32 + lk];
            float4 h0 = p[0], h1 = p[1];
            bf16x8 av;
            av[0] = (short)f2bf(h0.x); av[1] = (short)f2bf(h0.y);
            av[2] = (short)f2bf(h0.z); av[3] = (short)f2bf(h0.w);
            av[4] = (short)f2bf(h1.x); av[5] = (short)f2bf(h1.y);
            av[6] = (short)f2bf(h1.z); av[7] = (short)f2bf(h1.w);
            a[kk] = av;
        } else {
            a[kk] = *(const bf16x8*)&H[(size_t)arow * 128 + kk * 32 + lk];
        }
    }

    f32x4 acc[8] = {};
#pragma unroll
    for (int c = 0; c < 8; ++c) {
#pragma unroll
        for (int kk = 0; kk < 4; ++kk) {
            bf16x8 b = *(const bf16x8*)&WT[(size_t)(c * 16 + lr) * 128 + kk * 32 + lk];
            acc[c] = __builtin_amdgcn_mfma_f32_16x16x32_bf16(a[kk], b, acc[c], 0, 0, 0);
        }
    }

#pragma unroll
    for (int r = 0; r < 4; ++r) {
        int node = rowBase + (lane >> 4) * 4 + r;
        if (node < n) {
            float sc = dinv[node];
#pragma unroll
            for (int c = 0; c < 8; ++c)
                O[(size_t)node * 128 + c * 16 + lr] = f2bf(acc[c][r] * sc);
        }
    }
}

// ------- aggregation: 16 lanes/node, 4 nodes/wave, fp32 accum, bf16 out -------
template<bool RELU>
__global__ __launch_bounds__(256) void k_agg(const uint4* __restrict__ Hw,
                                             const int* __restrict__ rowptr,
                                             const float2* __restrict__ csr,
                                             const float* __restrict__ bias,
                                             unsigned short* __restrict__ out, int n) {
    int wv = threadIdx.x >> 6, lane = threadIdx.x & 63;
    int g = lane >> 4, sl = lane & 15;
    int node = blockIdx.x * 16 + wv * 4 + g;
    bool act = node < n;
    int s = 0, e = 0;
    if (act) { s = rowptr[node]; e = rowptr[node + 1]; }
    float a0 = 0.f, a1 = 0.f, a2 = 0.f, a3 = 0.f, a4 = 0.f, a5 = 0.f, a6 = 0.f, a7 = 0.f;

#define FMA8(V, W8) do {                                              \
    float _w = (W8);                                                  \
    a0 += __uint_as_float((V).x << 16) * _w;                          \
    a1 += __uint_as_float((V).x & 0xFFFF0000u) * _w;                  \
    a2 += __uint_as_float((V).y << 16) * _w;                          \
    a3 += __uint_as_float((V).y & 0xFFFF0000u) * _w;                  \
    a4 += __uint_as_float((V).z << 16) * _w;                          \
    a5 += __uint_as_float((V).z & 0xFFFF0000u) * _w;                  \
    a6 += __uint_as_float((V).w << 16) * _w;                          \
    a7 += __uint_as_float((V).w & 0xFFFF0000u) * _w;                  \
} while (0)

    int i = s;
    for (; i + 2 <= e; i += 2) {
        float2 p0 = csr[i], p1 = csr[i + 1];
        uint4 v0 = Hw[(size_t)__float_as_int(p0.x) * 16 + sl];
        uint4 v1 = Hw[(size_t)__float_as_int(p1.x) * 16 + sl];
        FMA8(v0, p0.y); FMA8(v1, p1.y);
    }
    if (i < e) {
        float2 pp = csr[i];
        uint4 v = Hw[(size_t)__float_as_int(pp.x) * 16 + sl];
        FMA8(v, pp.y);
    }
#undef FMA8

    if (act) {
        const float4* b4 = (const float4*)&bias[sl * 8];
        float4 b0 = b4[0], b1 = b4[1];
        a0 += b0.x; a1 += b0.y; a2 += b0.z; a3 += b0.w;
        a4 += b1.x; a5 += b1.y; a6 += b1.z; a7 += b1.w;
        if (RELU) {
            a0 = fmaxf(a0, 0.f); a1 = fmaxf(a1, 0.f); a2 = fmaxf(a2, 0.f); a3 = fmaxf(a3, 0.f);
            a4 = fmaxf(a4, 0.f); a5 = fmaxf(a5, 0.f); a6 = fmaxf(a6, 0.f); a7 = fmaxf(a7, 0.f);
        }
        ushort8 o;
        o[0] = f2bf(a0); o[1] = f2bf(a1); o[2] = f2bf(a2); o[3] = f2bf(a3);
        o[4] = f2bf(a4); o[5] = f2bf(a5); o[6] = f2bf(a6); o[7] = f2bf(a7);
        *(ushort8*)&out[(size_t)node * 128 + sl * 8] = o;
    }
}

// ---------------- fused mean-pool + final linear (bf16 input) ----------------
__device__ __forceinline__ int lower_bound_i(const int* a, int n, int key) {
    int lo = 0, hi = n;
    while (lo < hi) { int mid = (lo + hi) >> 1; if (a[mid] < key) lo = mid + 1; else hi = mid; }
    return lo;
}

__global__ void k_pool(const unsigned* __restrict__ H, const int* __restrict__ batch,
                       const float* __restrict__ Wlin, const float* __restrict__ blin,
                       float* __restrict__ out, int n) {
    int g = blockIdx.x;
    int start = lower_bound_i(batch, n, g);
    int end   = lower_bound_i(batch, n, g + 1);
    int t = threadIdx.x;
    int wid = t >> 6, lane = t & 63;
    float ax = 0.f, ay = 0.f;
    for (int i = start + wid; i < end; i += 4) {
        unsigned u = H[(size_t)i * 64 + lane];
        ax += __uint_as_float(u << 16);
        ay += __uint_as_float(u & 0xFFFF0000u);
    }
    __shared__ float ws[4][128];
    __shared__ float hg[128];
    ws[wid][lane * 2] = ax; ws[wid][lane * 2 + 1] = ay;
    __syncthreads();
    int cnt = end - start;
    float inv = 1.0f / fmaxf((float)cnt, 1.0f);
    if (t < 128) hg[t] = (ws[0][t] + ws[1][t] + ws[2][t] + ws[3][t]) * inv;
    __syncthreads();
    if (t < 16) {
        float s = blin[t];
        for (int ch = 0; ch < 128; ++ch) s += hg[ch] * Wlin[ch * 16 + t];
        out[g * 16 + t] = s;
    }
}

// ---------------- host ----------------
extern "C" void kernel_launch(void* const* d_in, const int* in_sizes, int n_in,
                              void* d_out, int out_size, void* d_ws, size_t ws_size,
                              hipStream_t stream) {
    const float* x    = (const float*)d_in[0];
    const int*   ei   = (const int*)d_in[1];
    const float* ew   = (const float*)d_in[2];
    const int*   batch= (const int*)d_in[3];
    const float* W1   = (const float*)d_in[4];
    const float* b1   = (const float*)d_in[5];
    const float* W2   = (const float*)d_in[6];
    const float* b2   = (const float*)d_in[7];
    const float* W3   = (const float*)d_in[8];
    const float* b3   = (const float*)d_in[9];
    const float* Wlin = (const float*)d_in[10];
    const float* blin = (const float*)d_in[11];
    float* out = (float*)d_out;

    int n  = in_sizes[0] / 128;
    int E  = in_sizes[2];
    int e2 = E + n;
    int G  = out_size / 16;
    const int* row = ei;
    const int* col = ei + E;

    int nbkt = (n + 255) >> 8;          // 256 nodes per bucket
    int M    = nbkt * NB;

    char* ws = (char*)d_ws;
    size_t off = 0;
    auto alloc = [&](size_t bytes) -> void* {
        void* p = ws + off;
        off = (off + bytes + 255) & ~255UL;
        return p;
    };
    // regionA: csrR (e2*8B) during pre; bf16 h (n*256B) after k_build
    size_t rawBytes = (size_t)e2 * 8;
    size_t hBytes   = (size_t)n * 128 * 2;
    void* regionA = alloc(rawBytes > hBytes ? rawBytes : hBytes);
    uint2*  csrR  = (uint2*)regionA;
    unsigned short* bufH = (unsigned short*)regionA;        // aliases csrR after k_build
    unsigned short* bufHw = (unsigned short*)alloc((size_t)n * 128 * 2);
    float2* csrF  = (float2*)alloc((size_t)e2 * 8);
    int*    cntA  = (int*)  alloc((size_t)M * 4);
    int*    S     = (int*)  alloc((size_t)(M + 1) * 4);
    int*    bsum  = (int*)  alloc(4096);
    float*  dinv  = (float*)alloc((size_t)n * 4);
    int*    rowptr= (int*)  alloc((size_t)(n + 1) * 4);
    unsigned short* WT1 = (unsigned short*)alloc(128 * 128 * 2);
    unsigned short* WT2 = (unsigned short*)alloc(128 * 128 * 2);
    unsigned short* WT3 = (unsigned short*)alloc(128 * 128 * 2);
    (void)ws_size;

    int per = (e2 + NB - 1) / NB;
    int nbScan = (M + SCAN_E - 1) / SCAN_E;

    // weight transpose+convert (independent; cheap)
    k_wt<<<64, 256, 0, stream>>>(W1, WT1);
    k_wt<<<64, 256, 0, stream>>>(W2, WT2);
    k_wt<<<64, 256, 0, stream>>>(W3, WT3);

    // dst counting sort + CSR build
    k_hist1<<<NB, 256, 0, stream>>>(col, E, e2, per, cntA, nbkt);
    k_scan_a<<<nbScan, SCAN_T, 0, stream>>>(cntA, M, S, bsum);
    k_scan_b<<<1, 128, 0, stream>>>(bsum, nbScan);
    k_scan_c<<<(M + 255) / 256, 256, 0, stream>>>(S, bsum, M, e2);
    k_scatter1<<<NB, 256, 0, stream>>>(row, col, ew, E, e2, per, S, csrR, nbkt);
    k_build<<<nbkt, 256, 0, stream>>>(csrR, S, n, e2, csrF, dinv, rowptr, nbkt);

    int gb = (n + 63) / 64;
    int ab = (n + 15) / 16;
    k_gemm_mfma<float><<<gb, 256, 0, stream>>>(x, WT1, dinv, bufHw, n);
    k_agg<true><<<ab, 256, 0, stream>>>((const uint4*)bufHw, rowptr, csrF, b1, bufH, n);
    k_gemm_mfma<unsigned short><<<gb, 256, 0, stream>>>(bufH, WT2, dinv, bufHw, n);
    k_agg<true><<<ab, 256, 0, stream>>>((const uint4*)bufHw, rowptr, csrF, b2, bufH, n);
    k_gemm_mfma<unsigned short><<<gb, 256, 0, stream>>>(bufH, WT3, dinv, bufHw, n);
    k_agg<false><<<ab, 256, 0, stream>>>((const uint4*)bufHw, rowptr, csrF, b3, bufH, n);
    k_pool<<<G, 256, 0, stream>>>((const unsigned*)bufH, batch, Wlin, blin, out, n);
}